// Round 6
// baseline (15.917 us; speedup 1.0000x reference)
//
#include <hip/hip_runtime.h>

#define B_ 16
#define Q_ 2048
#define K_ 1024
#define G_ 512
#define M_ 4096
#define NBLK 256  // 256 blocks x 16 waves x 1 pair/wave = 4096 pairs
#define MAGIC 0x5AD0C0DEu

__device__ __forceinline__ float bsum32(float v) {
#pragma unroll
  for (int o = 1; o < 32; o <<= 1) v += __shfl_xor(v, o, 64);
  return v;
}

__device__ __forceinline__ void corner_xy(float cx, float cy, float hx, float hy,
                                          float c, float s, int idx,
                                          float& x, float& y) {
  float sx = (idx < 2) ? 1.f : -1.f;
  float sy = (idx == 0 || idx == 3) ? 1.f : -1.f;
  float lx = sx * hx, ly = sy * hy;
  x = cx + lx * c - ly * s;
  y = cy + lx * s + ly * c;
}

// One wave per matched pair; single dispatch; block 0's wave 0 finalizes.
// Cross-block publication: self-validating relaxed u64 atomics (no release,
// no fences, no L2 writebacks).
__global__ __launch_bounds__(1024, 4) void fused_loss_kernel(
    const float* __restrict__ pred_boxes, const float* __restrict__ pred_ious,
    const float* __restrict__ gt_boxes, const int* __restrict__ topk_indexes,
    const int* __restrict__ batch_idx, const int* __restrict__ src_idx,
    const int* __restrict__ tgt_idx, const int* __restrict__ nb_ptr,
    float* __restrict__ out, unsigned long long* __restrict__ words) {
  const int tid = threadIdx.x;
  const int lane = tid & 63;
  const int wid = tid >> 6;
  const int blk = blockIdx.x;
  const int i = blk * 16 + wid;  // pair id

  // ---- uniform per-pair indices -> SGPRs -> s_load for boxes ----
  const int b = __builtin_amdgcn_readfirstlane(batch_idx[i]);
  const int s = __builtin_amdgcn_readfirstlane(src_idx[i]);
  const int t = __builtin_amdgcn_readfirstlane(tgt_idx[i]);
  const int tk = __builtin_amdgcn_readfirstlane(topk_indexes[b * K_ + s]);
  const float* mp = pred_boxes + ((size_t)b * Q_ + tk) * 7;
  const float* mt = gt_boxes + ((size_t)b * G_ + t) * 7;
  const float pim = pred_ious[b * Q_ + tk];
  float A[7], Bv[7];
#pragma unroll
  for (int j = 0; j < 7; ++j) { A[j] = mp[j]; Bv[j] = mt[j]; }

  // ---- loss_bbox / loss_rad ----
  float lb = 0.f;
#pragma unroll
  for (int j = 0; j < 6; ++j) lb += fabsf(A[j] - Bv[j]);
  float lr = fabsf(A[6] - Bv[6]);

  // ---- axis-aligned 3D GIoU on raw boxes (diagonal only) ----
  float lg;
  {
    float vol1 = 1.f, vol2 = 1.f, inter = 1.f, volc = 1.f;
#pragma unroll
    for (int j = 0; j < 3; ++j) {
      float l1 = A[j] - 0.5f * A[3 + j], r1 = A[j] + 0.5f * A[3 + j];
      float l2 = Bv[j] - 0.5f * Bv[3 + j], r2 = Bv[j] + 0.5f * Bv[3 + j];
      vol1 *= (r1 - l1);
      vol2 *= (r2 - l2);
      inter *= fmaxf(fminf(r1, r2) - fmaxf(l1, l2), 0.f);
      volc *= fmaxf(fmaxf(r1, r2) - fminf(l1, l2), 0.f);
    }
    float uni = vol1 + vol2 - inter;
    float iou = inter / fmaxf(uni, 1e-7f);
    lg = 1.f - (iou - (volc - uni) / fmaxf(volc, 1e-7f));
  }

  // ---- decode boxes ----
  float ax = A[0] * 150.4f - 75.2f;
  float ay = A[1] * 150.4f - 75.2f;
  float az = A[2] * 6.0f - 2.0f;
  float al = A[3] * 20.0f + 0.05f;
  float aw = A[4] * 20.0f + 0.05f;
  float ah = A[5] * 8.0f + 0.05f;
  float arad = A[6] * 6.2831853071795862f - 3.1415926535897931f;
  float bx = Bv[0] * 150.4f - 75.2f;
  float by = Bv[1] * 150.4f - 75.2f;
  float bz = Bv[2] * 6.0f - 2.0f;
  float bl = Bv[3] * 20.0f + 0.05f;
  float bw = Bv[4] * 20.0f + 0.05f;
  float bh = Bv[5] * 8.0f + 0.05f;
  float brad = Bv[6] * 6.2831853071795862f - 3.1415926535897931f;

  float cA = cosf(arad), sA = sinf(arad);
  float cB = cosf(brad), sB = sinf(brad);
  float ahx = al * 0.5f, ahy = aw * 0.5f;
  float bhx = bl * 0.5f, bhy = bw * 0.5f;

  // ---- per-lane candidate point ----
  float pxv = 0.f, pyv = 0.f;
  bool m = false;
  if (lane < 8) {
    bool isA = lane < 4;
    int ci = lane & 3;
    float ocx = isA ? ax : bx, ocy = isA ? ay : by;
    float ohx = isA ? ahx : bhx, ohy = isA ? ahy : bhy;
    float oc = isA ? cA : cB, os = isA ? sA : sB;
    float tcx = isA ? bx : ax, tcy = isA ? by : ay;
    float tl = isA ? bl : al, tw = isA ? bw : aw;
    float tc = isA ? cB : cA, ts = isA ? sB : sA;
    corner_xy(ocx, ocy, ohx, ohy, oc, os, ci, pxv, pyv);
    float dx = pxv - tcx, dy = pyv - tcy;
    float qx = dx * tc + dy * ts;
    float qy = -dx * ts + dy * tc;
    m = (fabsf(qx) <= tl * 0.5f + 1e-5f) && (fabsf(qy) <= tw * 0.5f + 1e-5f);
  } else if (lane < 24) {
    int e = lane - 8;
    int j = e >> 2, k = e & 3;
    float a0x, a0y, a1x, a1y, e0x, e0y, e1x, e1y;
    corner_xy(ax, ay, ahx, ahy, cA, sA, j, a0x, a0y);
    corner_xy(ax, ay, ahx, ahy, cA, sA, (j + 1) & 3, a1x, a1y);
    corner_xy(bx, by, bhx, bhy, cB, sB, k, e0x, e0y);
    corner_xy(bx, by, bhx, bhy, cB, sB, (k + 1) & 3, e1x, e1y);
    float dax = a1x - a0x, day = a1y - a0y;
    float dbx = e1x - e0x, dby = e1y - e0y;
    float dpx = e0x - a0x, dpy = e0y - a0y;
    float den = dax * dby - day * dbx;
    bool dok = fabsf(den) > 1e-8f;
    float dens = dok ? den : 1.f;
    float tt = (dpx * dby - dpy * dbx) / dens;
    float uu = (dpx * day - dpy * dax) / dens;
    m = dok && (tt >= 0.f) && (tt <= 1.f) && (uu >= 0.f) && (uu <= 1.f);
    pxv = a0x + tt * dax;
    pyv = a0y + tt * day;
  }

  // ---- centroid ----
  unsigned long long mb = __ballot(m);
  int cnt = __popcll(mb);
  float sx = bsum32(m ? pxv : 0.f);
  float sy = bsum32(m ? pyv : 0.f);
  float cd = fmaxf((float)cnt, 1.f);
  float cenx = sx / cd, ceny = sy / cd;

  // ---- diamond pseudo-angle (monotone-equivalent to atan2) ----
  float pdx = pxv - cenx, pdy = pyv - ceny;
  float ad = fabsf(pdx) + fabsf(pdy);
  float tq = pdy / ad;
  float pa = (pdx >= 0.f) ? tq : ((pdy >= 0.f) ? 2.f - tq : -2.f - tq);
  if (ad == 0.f) pa = 0.f;
  float ap = m ? pa : 1e9f;

  // ---- stable rank ----
  int r = 0;
#pragma unroll
  for (int q = 0; q < 24; ++q) {
    float aq = __shfl(ap, q, 64);
    r += (aq < ap || (aq == ap && q < lane)) ? 1 : 0;
  }
  if (lane >= 24) r = lane;

  // ---- scatter to rank order + shoelace ----
  float sxr = __int_as_float(__builtin_amdgcn_ds_permute(r << 2, __float_as_int(pxv)));
  float syr = __int_as_float(__builtin_amdgcn_ds_permute(r << 2, __float_as_int(pyv)));
  int nidx = ((lane + 1 == cnt) ? 0 : (lane + 1)) & 63;
  float nx = __int_as_float(__builtin_amdgcn_ds_bpermute(nidx << 2, __float_as_int(sxr)));
  float ny = __int_as_float(__builtin_amdgcn_ds_bpermute(nidx << 2, __float_as_int(syr)));
  float cr = (lane < cnt) ? (sxr * ny - nx * syr) : 0.f;
  float area2 = bsum32(cr);
  float area = 0.5f * fabsf(area2);
  float inter_bev = (cnt >= 3) ? area : 0.f;

  // ---- z overlap + 3D IoU + loss_iou ----
  float zlo = fmaxf(az - ah * 0.5f, bz - bh * 0.5f);
  float zhi = fminf(az + ah * 0.5f, bz + bh * 0.5f);
  float inter3 = inter_bev * fmaxf(zhi - zlo, 0.f);
  float v1 = al * aw * ah, v2 = bl * bw * bh;
  float iou3 = inter3 / fmaxf(v1 + v2 - inter3, 1e-7f);
  float li = fabsf(pim - (iou3 * 2.f - 1.f));

  // ---- block partial: 16 waves -> 4 self-validating u64 words ----
  __shared__ float4 wpart[16];
  if (lane == 0) wpart[wid] = make_float4(lb, lg, lr, li);
  __syncthreads();
  if (wid == 0) {
    float4 p = (lane < 16) ? wpart[lane] : make_float4(0.f, 0.f, 0.f, 0.f);
#pragma unroll
    for (int o = 1; o < 16; o <<= 1) {
      p.x += __shfl_xor(p.x, o, 64);
      p.y += __shfl_xor(p.y, o, 64);
      p.z += __shfl_xor(p.z, o, 64);
      p.w += __shfl_xor(p.w, o, 64);
    }
    if (lane == 0) {
      float pc0 = p.x, pc1 = p.y, pc2 = p.z, pc3 = p.w;
      // word layout: idx = cat*NBLK + blk; value = (MAGIC<<32)|float_bits
      __hip_atomic_store(&words[0 * NBLK + blk],
                         ((unsigned long long)MAGIC << 32) | (unsigned)__float_as_int(pc0),
                         __ATOMIC_RELAXED, __HIP_MEMORY_SCOPE_AGENT);
      __hip_atomic_store(&words[1 * NBLK + blk],
                         ((unsigned long long)MAGIC << 32) | (unsigned)__float_as_int(pc1),
                         __ATOMIC_RELAXED, __HIP_MEMORY_SCOPE_AGENT);
      __hip_atomic_store(&words[2 * NBLK + blk],
                         ((unsigned long long)MAGIC << 32) | (unsigned)__float_as_int(pc2),
                         __ATOMIC_RELAXED, __HIP_MEMORY_SCOPE_AGENT);
      __hip_atomic_store(&words[3 * NBLK + blk],
                         ((unsigned long long)MAGIC << 32) | (unsigned)__float_as_int(pc3),
                         __ATOMIC_RELAXED, __HIP_MEMORY_SCOPE_AGENT);
    }

    // ---- consumer: block 0, wave 0. lane = cat*16 + j; reads 16 blocks ----
    if (blk == 0) {
      const int cat = lane >> 4;
      const int base = (lane & 15) * 16;  // blocks [base, base+16)
      unsigned long long* myw = &words[cat * NBLK + base];
      float vals[16];
      unsigned pend = 0xFFFFu;
      while (pend) {
#pragma unroll
        for (int k = 0; k < 16; ++k) {
          if (pend & (1u << k)) {
            unsigned long long w = __hip_atomic_load(&myw[k], __ATOMIC_RELAXED,
                                                     __HIP_MEMORY_SCOPE_AGENT);
            if ((unsigned)(w >> 32) == MAGIC) {
              vals[k] = __int_as_float((int)(unsigned)w);
              pend &= ~(1u << k);
            }
          }
        }
        if (pend) __builtin_amdgcn_s_sleep(1);
      }
      // fixed-order accumulate (deterministic)
      float ssum = 0.f;
#pragma unroll
      for (int k = 0; k < 16; ++k) ssum += vals[k];
      // reduce across the 16 lanes of this category (xor stays in group)
#pragma unroll
      for (int o = 1; o < 16; o <<= 1) ssum += __shfl_xor(ssum, o, 64);
      float t0 = __shfl(ssum, 0, 64);
      float t1 = __shfl(ssum, 16, 64);
      float t2 = __shfl(ssum, 32, 64);
      float t3 = __shfl(ssum, 48, 64);
      if (lane == 0) {
        float nb = (float)nb_ptr[0];
        out[0] = t0 / nb;
        out[1] = t1 / nb;
        out[2] = t2 / nb;
        out[3] = t3 / nb;
      }
      // reset words for the next stream-ordered call
#pragma unroll
      for (int k = 0; k < 16; ++k) {
        __hip_atomic_store(&myw[k], 0ULL, __ATOMIC_RELAXED,
                           __HIP_MEMORY_SCOPE_AGENT);
      }
    }
  }
}

extern "C" void kernel_launch(void* const* d_in, const int* in_sizes, int n_in,
                              void* d_out, int out_size, void* d_ws, size_t ws_size,
                              hipStream_t stream) {
  const float* pred_boxes = (const float*)d_in[0];
  const float* pred_ious  = (const float*)d_in[1];
  const float* gt_boxes   = (const float*)d_in[2];
  const int* topk         = (const int*)d_in[3];
  const int* bidx         = (const int*)d_in[4];
  const int* sidx         = (const int*)d_in[5];
  const int* tidx         = (const int*)d_in[6];
  const int* nb           = (const int*)d_in[7];
  unsigned long long* words = (unsigned long long*)d_ws;  // 4*NBLK u64 = 8 KiB

  fused_loss_kernel<<<dim3(NBLK), dim3(1024), 0, stream>>>(
      pred_boxes, pred_ious, gt_boxes, topk, bidx, sidx, tidx, nb,
      (float*)d_out, words);
}

// Round 7
// 12.766 us; speedup vs baseline: 1.2468x; 1.2468x over previous
//
#include <hip/hip_runtime.h>

#define B_ 16
#define Q_ 2048
#define K_ 1024
#define G_ 512
#define M_ 4096

__device__ __forceinline__ float bsum32(float v) {
#pragma unroll
  for (int o = 1; o < 32; o <<= 1) v += __shfl_xor(v, o, 64);
  return v;  // lanes 0-31 hold sum over their 32-lane half
}

__device__ __forceinline__ void corner_xy(float cx, float cy, float hx, float hy,
                                          float c, float s, int idx,
                                          float& x, float& y) {
  // sgx = {+,+,-,-}[idx], sgy = {+,-,-,+}[idx]
  float sx = (idx < 2) ? 1.f : -1.f;
  float sy = (idx == 0 || idx == 3) ? 1.f : -1.f;
  float lx = sx * hx, ly = sy * hy;
  x = cx + lx * c - ly * s;
  y = cy + lx * s + ly * c;
}

// One wave (64 lanes) per matched pair. Lane p owns candidate point p (p<24).
__global__ __launch_bounds__(256, 4) void pair_loss_kernel(
    const float* __restrict__ pred_boxes, const float* __restrict__ pred_ious,
    const float* __restrict__ gt_boxes, const int* __restrict__ topk_indexes,
    const int* __restrict__ batch_idx, const int* __restrict__ src_idx,
    const int* __restrict__ tgt_idx, float* __restrict__ partials) {
  const int lane = threadIdx.x & 63;
  const int wid = threadIdx.x >> 6;
  const int i = blockIdx.x * 4 + wid;  // pair id, grid = M/4 blocks

  // ---- uniform per-pair indices: force into SGPRs -> s_load for boxes ----
  const int b = __builtin_amdgcn_readfirstlane(batch_idx[i]);
  const int s = __builtin_amdgcn_readfirstlane(src_idx[i]);
  const int t = __builtin_amdgcn_readfirstlane(tgt_idx[i]);
  const int tk = __builtin_amdgcn_readfirstlane(topk_indexes[b * K_ + s]);
  const float* mp = pred_boxes + ((size_t)b * Q_ + tk) * 7;
  const float* mt = gt_boxes + ((size_t)b * G_ + t) * 7;
  const float pim = pred_ious[b * Q_ + tk];
  float A[7], Bv[7];
#pragma unroll
  for (int j = 0; j < 7; ++j) { A[j] = mp[j]; Bv[j] = mt[j]; }

  // ---- loss_bbox / loss_rad (raw boxes) ----
  float lb = 0.f;
#pragma unroll
  for (int j = 0; j < 6; ++j) lb += fabsf(A[j] - Bv[j]);
  float lr = fabsf(A[6] - Bv[6]);

  // ---- axis-aligned 3D GIoU on raw boxes (diagonal only) ----
  float lg;
  {
    float vol1 = 1.f, vol2 = 1.f, inter = 1.f, volc = 1.f;
#pragma unroll
    for (int j = 0; j < 3; ++j) {
      float l1 = A[j] - 0.5f * A[3 + j], r1 = A[j] + 0.5f * A[3 + j];
      float l2 = Bv[j] - 0.5f * Bv[3 + j], r2 = Bv[j] + 0.5f * Bv[3 + j];
      vol1 *= (r1 - l1);
      vol2 *= (r2 - l2);
      inter *= fmaxf(fminf(r1, r2) - fmaxf(l1, l2), 0.f);
      volc *= fmaxf(fmaxf(r1, r2) - fminf(l1, l2), 0.f);
    }
    float uni = vol1 + vol2 - inter;
    float iou = inter / fmaxf(uni, 1e-7f);
    lg = 1.f - (iou - (volc - uni) / fmaxf(volc, 1e-7f));
  }

  // ---- decode boxes ----
  float ax = A[0] * 150.4f - 75.2f;
  float ay = A[1] * 150.4f - 75.2f;
  float az = A[2] * 6.0f - 2.0f;
  float al = A[3] * 20.0f + 0.05f;
  float aw = A[4] * 20.0f + 0.05f;
  float ah = A[5] * 8.0f + 0.05f;
  float arad = A[6] * 6.2831853071795862f - 3.1415926535897931f;
  float bx = Bv[0] * 150.4f - 75.2f;
  float by = Bv[1] * 150.4f - 75.2f;
  float bz = Bv[2] * 6.0f - 2.0f;
  float bl = Bv[3] * 20.0f + 0.05f;
  float bw = Bv[4] * 20.0f + 0.05f;
  float bh = Bv[5] * 8.0f + 0.05f;
  float brad = Bv[6] * 6.2831853071795862f - 3.1415926535897931f;

  float cA = cosf(arad), sA = sinf(arad);
  float cB = cosf(brad), sB = sinf(brad);
  float ahx = al * 0.5f, ahy = aw * 0.5f;
  float bhx = bl * 0.5f, bhy = bw * 0.5f;

  // ---- per-lane candidate point ----
  float pxv = 0.f, pyv = 0.f;
  bool m = false;
  if (lane < 8) {
    // corners: lanes 0-3 of A (tested vs B), 4-7 of B (tested vs A)
    bool isA = lane < 4;
    int ci = lane & 3;
    float ocx = isA ? ax : bx, ocy = isA ? ay : by;
    float ohx = isA ? ahx : bhx, ohy = isA ? ahy : bhy;
    float oc = isA ? cA : cB, os = isA ? sA : sB;
    float tcx = isA ? bx : ax, tcy = isA ? by : ay;
    float tl = isA ? bl : al, tw = isA ? bw : aw;
    float tc = isA ? cB : cA, ts = isA ? sB : sA;
    corner_xy(ocx, ocy, ohx, ohy, oc, os, ci, pxv, pyv);
    float dx = pxv - tcx, dy = pyv - tcy;
    float qx = dx * tc + dy * ts;
    float qy = -dx * ts + dy * tc;
    m = (fabsf(qx) <= tl * 0.5f + 1e-5f) && (fabsf(qy) <= tw * 0.5f + 1e-5f);
  } else if (lane < 24) {
    int e = lane - 8;
    int j = e >> 2, k = e & 3;
    float a0x, a0y, a1x, a1y, e0x, e0y, e1x, e1y;
    corner_xy(ax, ay, ahx, ahy, cA, sA, j, a0x, a0y);
    corner_xy(ax, ay, ahx, ahy, cA, sA, (j + 1) & 3, a1x, a1y);
    corner_xy(bx, by, bhx, bhy, cB, sB, k, e0x, e0y);
    corner_xy(bx, by, bhx, bhy, cB, sB, (k + 1) & 3, e1x, e1y);
    float dax = a1x - a0x, day = a1y - a0y;
    float dbx = e1x - e0x, dby = e1y - e0y;
    float dpx = e0x - a0x, dpy = e0y - a0y;
    float den = dax * dby - day * dbx;
    bool dok = fabsf(den) > 1e-8f;
    float dens = dok ? den : 1.f;
    float tt = (dpx * dby - dpy * dbx) / dens;
    float uu = (dpx * day - dpy * dax) / dens;
    m = dok && (tt >= 0.f) && (tt <= 1.f) && (uu >= 0.f) && (uu <= 1.f);
    pxv = a0x + tt * dax;
    pyv = a0y + tt * day;
  }

  // ---- centroid over masked points (lanes 24-63 contribute 0) ----
  unsigned long long mb = __ballot(m);
  int cnt = __popcll(mb);
  float sx = bsum32(m ? pxv : 0.f);
  float sy = bsum32(m ? pyv : 0.f);
  float cd = fmaxf((float)cnt, 1.f);
  float cenx = sx / cd, ceny = sy / cd;  // valid on lanes 0-31 (all that matter)

  // ---- diamond pseudo-angle: strictly monotone in atan2 over [-pi,pi] ----
  // Same sort order as atan2; exact duplicates of (px,py) produce bitwise
  // equal pseudo-angles, so stable tie-break by lane matches the reference.
  float pdx = pxv - cenx, pdy = pyv - ceny;
  float ad = fabsf(pdx) + fabsf(pdy);
  float tq = pdy / ad;
  float pa = (pdx >= 0.f) ? tq : ((pdy >= 0.f) ? 2.f - tq : -2.f - tq);
  if (ad == 0.f) pa = 0.f;  // atan2(0,0)=0
  float ap = m ? pa : 1e9f;

  // ---- stable rank among the 24 candidates ----
  int r = 0;
#pragma unroll
  for (int q = 0; q < 24; ++q) {
    float aq = __shfl(ap, q, 64);
    r += (aq < ap || (aq == ap && q < lane)) ? 1 : 0;
  }
  if (lane >= 24) r = lane;  // keep permutation bijective over 64 lanes

  // ---- scatter points to rank order (in-register) ----
  float sxr = __int_as_float(__builtin_amdgcn_ds_permute(r << 2, __float_as_int(pxv)));
  float syr = __int_as_float(__builtin_amdgcn_ds_permute(r << 2, __float_as_int(pyv)));

  // ---- shoelace over sorted masked points (== reference p0-padded loop) ----
  int nidx = ((lane + 1 == cnt) ? 0 : (lane + 1)) & 63;
  float nx = __int_as_float(__builtin_amdgcn_ds_bpermute(nidx << 2, __float_as_int(sxr)));
  float ny = __int_as_float(__builtin_amdgcn_ds_bpermute(nidx << 2, __float_as_int(syr)));
  float cr = (lane < cnt) ? (sxr * ny - nx * syr) : 0.f;
  float area2 = bsum32(cr);  // lanes < 32 valid; only lane 0 consumes
  float area = 0.5f * fabsf(area2);
  float inter_bev = (cnt >= 3) ? area : 0.f;

  // ---- z overlap + 3D IoU + loss_iou ----
  float zlo = fmaxf(az - ah * 0.5f, bz - bh * 0.5f);
  float zhi = fminf(az + ah * 0.5f, bz + bh * 0.5f);
  float inter3 = inter_bev * fmaxf(zhi - zlo, 0.f);
  float v1 = al * aw * ah, v2 = bl * bw * bh;
  float iou3 = inter3 / fmaxf(v1 + v2 - inter3, 1e-7f);
  float li = fabsf(pim - (iou3 * 2.f - 1.f));

  // ---- block partial: 4 waves -> 1 float4 ----
  __shared__ float wpart[4][4];
  if (lane == 0) {
    wpart[wid][0] = lb;
    wpart[wid][1] = lg;
    wpart[wid][2] = lr;
    wpart[wid][3] = li;
  }
  __syncthreads();
  if (threadIdx.x == 0) {
    float4 o;
    o.x = wpart[0][0] + wpart[1][0] + wpart[2][0] + wpart[3][0];
    o.y = wpart[0][1] + wpart[1][1] + wpart[2][1] + wpart[3][1];
    o.z = wpart[0][2] + wpart[1][2] + wpart[2][2] + wpart[3][2];
    o.w = wpart[0][3] + wpart[1][3] + wpart[2][3] + wpart[3][3];
    ((float4*)partials)[blockIdx.x] = o;
  }
}

__global__ __launch_bounds__(256) void finalize_kernel(
    const float* __restrict__ partials, const int* __restrict__ nb_ptr,
    float* __restrict__ out) {
  const int tid = threadIdx.x;
  const int lane = tid & 63;
  const int wid = tid >> 6;
  float4 acc = make_float4(0.f, 0.f, 0.f, 0.f);
#pragma unroll
  for (int k = 0; k < 4; ++k) {
    float4 p = ((const float4*)partials)[tid + 256 * k];
    acc.x += p.x; acc.y += p.y; acc.z += p.z; acc.w += p.w;
  }
#pragma unroll
  for (int o = 1; o < 64; o <<= 1) {
    acc.x += __shfl_xor(acc.x, o, 64);
    acc.y += __shfl_xor(acc.y, o, 64);
    acc.z += __shfl_xor(acc.z, o, 64);
    acc.w += __shfl_xor(acc.w, o, 64);
  }
  __shared__ float wpart[4][4];
  if (lane == 0) {
    wpart[wid][0] = acc.x; wpart[wid][1] = acc.y;
    wpart[wid][2] = acc.z; wpart[wid][3] = acc.w;
  }
  __syncthreads();
  if (tid == 0) {
    float nb = (float)nb_ptr[0];
    out[0] = (wpart[0][0] + wpart[1][0] + wpart[2][0] + wpart[3][0]) / nb;
    out[1] = (wpart[0][1] + wpart[1][1] + wpart[2][1] + wpart[3][1]) / nb;
    out[2] = (wpart[0][2] + wpart[1][2] + wpart[2][2] + wpart[3][2]) / nb;
    out[3] = (wpart[0][3] + wpart[1][3] + wpart[2][3] + wpart[3][3]) / nb;
  }
}

extern "C" void kernel_launch(void* const* d_in, const int* in_sizes, int n_in,
                              void* d_out, int out_size, void* d_ws, size_t ws_size,
                              hipStream_t stream) {
  const float* pred_boxes = (const float*)d_in[0];
  const float* pred_ious  = (const float*)d_in[1];
  const float* gt_boxes   = (const float*)d_in[2];
  const int* topk         = (const int*)d_in[3];
  const int* bidx         = (const int*)d_in[4];
  const int* sidx         = (const int*)d_in[5];
  const int* tidx         = (const int*)d_in[6];
  const int* nb           = (const int*)d_in[7];
  float* partials = (float*)d_ws;  // 1024 blocks * float4 = 16 KiB

  pair_loss_kernel<<<dim3(M_ / 4), dim3(256), 0, stream>>>(
      pred_boxes, pred_ious, gt_boxes, topk, bidx, sidx, tidx, partials);
  finalize_kernel<<<dim3(1), dim3(256), 0, stream>>>(partials, nb, (float*)d_out);
}